// Round 14
// baseline (274.421 us; speedup 1.0000x reference)
//
#include <hip/hip_runtime.h>
#include <hip/hip_bf16.h>

// ---------------------------------------------------------------------------
// VisionLinearAttention: x->bf16 prep, patch-embed (all-bf16 MFMA GEMM with
// fused bias+PE+softmax epilogue, bf16 outputs) -> scores = ek^T v ->
// ctx = qn @ S.
//
// Shapes: B=16, C=3, H=W=512, PATCH=16 -> N=1024 tokens, D=1024, K=768,
//         heads=16, hd=64.  M = B*N = 16384.
//
// t-region semantics after k_embed (ALL bf16):
//   z=0: qn  = softmax over head_dim of (q+bias+pe)   in [0,1]
//   z=1: ek  = exp(k+bias+pe)                          <= ~67
//   z=2: v   = v+bias+pe                               ~ +-5
//
// Workspace map (bytes):
//   0x0000000  t_bf[3][16384][1024] bf16  96 MiB
//   0x6000000  wbf[3][1024][768]  bf16    4.5 MiB
//   0x6480000  pe[1024][1024] f32         4 MiB
//   0x6880000  scores[256][64][64] f32    4 MiB
//   0x6C80000  x_bf[3][12582912] bf16     72 MiB   (total 189.5 MiB;
//                                        ws >= 214.5 MiB proven in r3-r8)
//
// R13 confirmed the L2 model: 3 blocks/CU residency -> FETCH 135MB, 125us.
// R14 applies R8's proven counted-vmcnt raw-barrier dbuf (T4) at BK=64:
// 64KB LDS self-caps at 2 blocks/CU (same occupancy as R13's measured 26%),
// but the 8 staging loads stay in flight across the compute phase instead
// of being drained by __syncthreads' vmcnt(0).
// ---------------------------------------------------------------------------

typedef float  f32x4  __attribute__((ext_vector_type(4)));
typedef __bf16 bf16x8 __attribute__((ext_vector_type(8)));
typedef __bf16 bf16x4 __attribute__((ext_vector_type(4)));

#define LN10000 9.210340371976184f

__device__ __forceinline__ unsigned short f2bf_bits(float f){
  union { float f; unsigned u; } a; a.f = f;
  unsigned r = a.u + 0x7FFFu + ((a.u >> 16) & 1u);   // round-to-nearest-even
  return (unsigned short)(r >> 16);
}

__device__ __forceinline__ void gload16(const void* g, void* l){
  __builtin_amdgcn_global_load_lds((__attribute__((address_space(1))) void*)g,
                                   (__attribute__((address_space(3))) void*)l,
                                   16, 0, 0);
}

// --------------------------- prep kernels ----------------------------------

__global__ __launch_bounds__(256) void k_prep_w(
    const float* __restrict__ wq, const float* __restrict__ wk,
    const float* __restrict__ wv, unsigned short* __restrict__ wbf)
{
  int i = blockIdx.x*256 + threadIdx.x;      // quad index, 3*786432/4 = 589824
  if (i >= 589824) return;
  int z = i / 196608;
  int r = i - z*196608;
  const float* src = (z==0) ? wq : (z==1 ? wk : wv);
  f32x4 v = ((const f32x4*)src)[r];
  unsigned lo = (unsigned)f2bf_bits(v[0]) | ((unsigned)f2bf_bits(v[1]) << 16);
  unsigned hh = (unsigned)f2bf_bits(v[2]) | ((unsigned)f2bf_bits(v[3]) << 16);
  ((uint2*)wbf)[i] = make_uint2(lo, hh);
}

__global__ __launch_bounds__(256) void k_prep_pe(float* __restrict__ pe)
{
  int i = blockIdx.x*256 + threadIdx.x;      // 1024*1024
  if (i >= 1048576) return;
  int n = i >> 10, dd = i & 1023;
  float ex  = (float)(dd & ~1) * (1.0f/1024.0f);
  float ang = (float)n * expf(-LN10000 * ex);
  pe[i] = (dd & 1) ? cosf(ang) : sinf(ang);
}

// x (3 images, f32) -> bf16, flat same layout.  8 elems / thread.
__global__ __launch_bounds__(256) void k_prep_x(
    const float* __restrict__ xq, const float* __restrict__ xk,
    const float* __restrict__ xv, unsigned short* __restrict__ x_bf)
{
  int i = blockIdx.x*256 + threadIdx.x;      // 8-elem unit; 4718592 total
  if (i >= 4718592) return;
  int z = i / 1572864;
  int r = i - z*1572864;
  const float* src = (z==0) ? xq : (z==1 ? xk : xv);
  f32x4 a = ((const f32x4*)src)[r*2];
  f32x4 b = ((const f32x4*)src)[r*2+1];
  uint4 o;
  o.x = (unsigned)f2bf_bits(a[0]) | ((unsigned)f2bf_bits(a[1]) << 16);
  o.y = (unsigned)f2bf_bits(a[2]) | ((unsigned)f2bf_bits(a[3]) << 16);
  o.z = (unsigned)f2bf_bits(b[0]) | ((unsigned)f2bf_bits(b[1]) << 16);
  o.w = (unsigned)f2bf_bits(b[2]) | ((unsigned)f2bf_bits(b[3]) << 16);
  ((uint4*)x_bf)[i] = o;
}

// --------------------------- patch-embed GEMM ------------------------------
// 128x128 tile, BK=64, 4 waves (2x2), 4x4 mfma 16x16x32.  All-bf16 staging
// via global_load_lds (both operands, 128 B rows, XOR swizzle both sides).
// COUNTED-VMCNT DOUBLE-BUFFER (R8's proven sync skeleton):
//   iter ks: STAGE(buf^1, ks+1) [8 loads]; s_waitcnt vmcnt(8)  (cur landed)
//            sched_barrier; s_barrier; sched_barrier;
//            ds_read+MFMA from buf[cur];
//            sched_barrier; s_barrier;   (reads done before cur re-staged)
// Hazards: stale-read covered by vmcnt(8)+barrier#1; WAR by barrier#2;
// uniform control flow.  LDS 64 KiB -> 2 blocks/CU (≈ R13's measured
// occupancy, and A-panel working set ~1.5 MiB/XCD << 4 MiB L2).

__global__ __launch_bounds__(256, 2) void k_embed(
    const unsigned short* __restrict__ x_bf,
    const unsigned short* __restrict__ wbf,
    const float* __restrict__ bq, const float* __restrict__ bk,
    const float* __restrict__ bv, const float* __restrict__ pe,
    unsigned short* __restrict__ t_bf)
{
  __shared__ __align__(16) unsigned short ldsA[2][128*64];   // 2 x 16 KiB
  __shared__ __align__(16) unsigned short ldsB[2][128*64];   // 2 x 16 KiB

  const int tid = threadIdx.x;
  // XCD swizzle: orig tile id = (flat&7)*384 + (flat>>3).  3072 = 8*384,
  // 384%8==0, so each m-tile's 8 consecutive d-tiles share flat&7 (one XCD).
  int flat = blockIdx.x + (blockIdx.y << 3) + (blockIdx.z << 10); // 0..3071
  int orig = (flat & 7)*384 + (flat >> 3);
  const int z   = orig >> 10;
  const int rem = orig & 1023;
  const int m0  = (rem >> 3) * 128;
  const int d0  = (rem & 7) * 128;

  const unsigned short* xbz = x_bf + (size_t)z*12582912u;
  const unsigned short* wz  = wbf + z*786432;
  const float* bias = (z==0) ? bq : (z==1 ? bk : bv);
  unsigned short* tout = t_bf + (size_t)z*16777216u;

  // ---- A staging map: dest byte L = i*4096 + tid*16, 128 B rows, 4 loads.
  // aKK = bf16 element offset within the 64-wide k-slice (multiple of 8).
  int aRowG[4], aKK[4];
#pragma unroll
  for (int i=0;i<4;i++){
    int L   = i*4096 + tid*16;
    int row = L >> 7;                   // 0..127
    int U   = L ^ ((row & 7) << 4);     // inverse-swizzled source slot
    aKK[i]  = (U & 127) >> 1;
    int m   = m0 + row;
    int bimg = m >> 10, nt = m & 1023;
    aRowG[i] = bimg*786432 + (nt>>5)*8192 + (nt&31)*16;
  }
  // ---- B staging map: identical structure ----
  int bOff[4];
#pragma unroll
  for (int i=0;i<4;i++){
    int L   = i*4096 + tid*16;
    int row = L >> 7;
    int U   = L ^ ((row & 7) << 4);
    bOff[i] = (d0 + row)*768 + ((U >> 1) & 63);
  }

  const int lane = tid & 63;
  const int wid  = tid >> 6;
  const int ln   = lane & 15, hi4 = lane >> 4;
  const int wm   = wid >> 1,  wn  = wid & 1;

  f32x4 acc[4][4] = {};

#define STAGE(BUF, KS) do{                                                  \
    _Pragma("unroll")                                                       \
    for (int i=0;i<4;i++){                                                  \
      int k  = (KS)*64 + aKK[i];                                            \
      int c  = k >> 8, r2 = k & 255;                                        \
      gload16(xbz + aRowG[i] + c*262144 + (r2>>4)*512 + (r2 & 15),          \
              (char*)(&ldsA[BUF][0]) + i*4096 + wid*1024);                  \
    }                                                                       \
    _Pragma("unroll")                                                       \
    for (int i=0;i<4;i++){                                                  \
      gload16(wz + bOff[i] + (KS)*64,                                       \
              (char*)(&ldsB[BUF][0]) + i*4096 + wid*1024);                  \
    } }while(0)

  STAGE(0, 0);
  for (int ks=0; ks<12; ++ks){
    int cur = ks & 1;
    if (ks < 11){
      STAGE(cur^1, ks+1);               // 8 async loads into OTHER buffer
      asm volatile("s_waitcnt vmcnt(8)" ::: "memory");  // cur's 8 landed
    } else {
      asm volatile("s_waitcnt vmcnt(0)" ::: "memory");
    }
    __builtin_amdgcn_sched_barrier(0);
    __builtin_amdgcn_s_barrier();       // all waves: cur staged
    __builtin_amdgcn_sched_barrier(0);

    const char* pA = (const char*)&ldsA[cur][0];
    const char* pB = (const char*)&ldsB[cur][0];
#pragma unroll
    for (int kc=0; kc<2; ++kc){
      bf16x8 af[4], bfr[4];
#pragma unroll
      for (int mi=0;mi<4;mi++){
        int row  = wm*64 + mi*16 + ln;
        int byte = (row*128 + kc*64 + hi4*16) ^ ((row & 7) << 4);
        af[mi] = *(const bf16x8*)(pA + byte);
      }
#pragma unroll
      for (int ni=0;ni<4;ni++){
        int row  = wn*64 + ni*16 + ln;
        int byte = (row*128 + kc*64 + hi4*16) ^ ((row & 7) << 4);
        bfr[ni] = *(const bf16x8*)(pB + byte);
      }
#pragma unroll
      for (int mi=0;mi<4;mi++)
#pragma unroll
        for (int ni=0;ni<4;ni++)
          acc[mi][ni] = __builtin_amdgcn_mfma_f32_16x16x32_bf16(
              af[mi], bfr[ni], acc[mi][ni], 0, 0, 0);
    }

    __builtin_amdgcn_sched_barrier(0);
    __builtin_amdgcn_s_barrier();       // reads of cur done before re-stage
  }
#undef STAGE

  // ---- fused epilogue: + bias + PE, per-tensor transform, bf16 store ----
  // This wave's 64 output cols = exactly one head (d0 + wn*64 .. +63).
  float bias4[4];
#pragma unroll
  for (int ni=0;ni<4;ni++) bias4[ni] = bias[d0 + wn*64 + ni*16 + ln];

#pragma unroll
  for (int mi=0;mi<4;mi++){
#pragma unroll
    for (int r=0;r<4;r++){
      int m    = m0 + wm*64 + mi*16 + hi4*4 + r;
      int ntok = m & 1023;
      float vv[4];
#pragma unroll
      for (int ni=0;ni<4;ni++){
        int dd = d0 + wn*64 + ni*16 + ln;
        vv[ni] = acc[mi][ni][r] + bias4[ni] + pe[ntok*1024 + dd];
      }
      size_t base = (size_t)m*1024 + d0 + wn*64 + ln;
      if (z == 0){
        // softmax over the 64-dim head: 4 per-thread + 16-lane shfl group
        // (the 16-lane group = contiguous lanes sharing hi4 -> same row m)
        float ex0=__expf(vv[0]), ex1=__expf(vv[1]),
              ex2=__expf(vv[2]), ex3=__expf(vv[3]);
        float ps = ex0+ex1+ex2+ex3;
        ps += __shfl_xor(ps, 1); ps += __shfl_xor(ps, 2);
        ps += __shfl_xor(ps, 4); ps += __shfl_xor(ps, 8);
        float w = 1.0f / ps;
        tout[base +  0] = f2bf_bits(ex0*w);  tout[base + 16] = f2bf_bits(ex1*w);
        tout[base + 32] = f2bf_bits(ex2*w);  tout[base + 48] = f2bf_bits(ex3*w);
      } else if (z == 1){
        tout[base +  0] = f2bf_bits(__expf(vv[0]));
        tout[base + 16] = f2bf_bits(__expf(vv[1]));
        tout[base + 32] = f2bf_bits(__expf(vv[2]));
        tout[base + 48] = f2bf_bits(__expf(vv[3]));
      } else {
        tout[base +  0] = f2bf_bits(vv[0]); tout[base + 16] = f2bf_bits(vv[1]);
        tout[base + 32] = f2bf_bits(vv[2]); tout[base + 48] = f2bf_bits(vv[3]);
      }
    }
  }
}

// --------------------------- scores = ek^T v -------------------------------
// One block (512 threads = 16 waves) per (b,h).  ek,v read as bf16 (16 B
// per lane), converted to f32 in LDS.  Proven 2-phase dbuf skeleton over 16
// chunks of 64 tokens; npart in [0,8) splits tokens; two-step quadrant
// reduction; ksum folded; S stored normalized f32.   (proven r11-r13)

__global__ __launch_bounds__(512) void k_scores(
    const __bf16* __restrict__ t_bf, float* __restrict__ scoresOut)
{
  __shared__ __align__(16) float lds[4][4096];  // [0],[1]=ek dbuf; [2],[3]=v dbuf
  __shared__ float ksumLds[8][64];

  const int tid = threadIdx.x;                // 0..511
  const int bh  = blockIdx.x;
  const int b   = bh >> 4, h = bh & 15;
  const __bf16* kbase = t_bf + 16777216u + (size_t)b*1048576u + h*64;
  const __bf16* vbase = t_bf + 33554432u + (size_t)b*1048576u + h*64;

  const int dq = tid & 15, eg = (tid>>4) & 3, npart = tid >> 6;  // npart 0..7
  const int srow = tid >> 3;        // 0..63 (stage row; 8 threads/row)
  const int dcol = (tid & 7) * 8;   // bf16 elem col within the 64-dim slice

#define STAGE(BUF, CH) do{                                                \
    size_t g = (size_t)((CH)*64 + srow)*1024 + dcol;                      \
    bf16x8 k8 = *(const bf16x8*)(kbase + g);                              \
    bf16x8 v8 = *(const bf16x8*)(vbase + g);                              \
    f32x4 e0, e1, w0, w1;                                                 \
    e0[0]=(float)k8[0]; e0[1]=(float)k8[1]; e0[2]=(float)k8[2]; e0[3]=(float)k8[3]; \
    e1[0]=(float)k8[4]; e1[1]=(float)k8[5]; e1[2]=(float)k8[6]; e1[3]=(float)k8[7]; \
    w0[0]=(float)v8[0]; w0[1]=(float)v8[1]; w0[2]=(float)v8[2]; w0[3]=(float)v8[3]; \
    w1[0]=(float)v8[4]; w1[1]=(float)v8[5]; w1[2]=(float)v8[6]; w1[3]=(float)v8[7]; \
    *(f32x4*)(&lds[BUF][srow*64 + dcol])       = e0;                      \
    *(f32x4*)(&lds[BUF][srow*64 + dcol + 4])   = e1;                      \
    *(f32x4*)(&lds[2+(BUF)][srow*64 + dcol])     = w0;                    \
    *(f32x4*)(&lds[2+(BUF)][srow*64 + dcol + 4]) = w1;                    \
  }while(0)

  float acc[4][16] = {};
  float kp[4] = {0.f,0.f,0.f,0.f};

  STAGE(0, 0);
  __syncthreads();
  for (int ch=0; ch<16; ++ch){
    int cur = ch & 1;
    if (ch < 15) STAGE(cur^1, ch+1);   // writes OTHER buffer: safe vs compute
    for (int nn = npart; nn < 64; nn += 8){
      f32x4 ek4 = *(const f32x4*)(&lds[cur][nn*64 + dq*4]);
      f32x4 v0  = *(const f32x4*)(&lds[2+cur][nn*64 + eg*16 + 0]);
      f32x4 v1  = *(const f32x4*)(&lds[2+cur][nn*64 + eg*16 + 4]);
      f32x4 v2  = *(const f32x4*)(&lds[2+cur][nn*64 + eg*16 + 8]);
      f32x4 v3  = *(const f32x4*)(&lds[2+cur][nn*64 + eg*16 + 12]);
#pragma unroll
      for (int i2=0;i2<4;i2++){
        kp[i2] += ek4[i2];
#pragma unroll
        for (int j=0;j<4;j++){
          acc[i2][j+0]  += ek4[i2]*v0[j];
          acc[i2][j+4]  += ek4[i2]*v1[j];
          acc[i2][j+8]  += ek4[i2]*v2[j];
          acc[i2][j+12] += ek4[i2]*v3[j];
        }
      }
    }
    __syncthreads();
  }
#undef STAGE

  // kp identical across the 16 eg threads of a (dq,npart); eg==0 publishes.
  if (eg == 0){
#pragma unroll
    for (int i2=0;i2<4;i2++) ksumLds[npart][dq*4 + i2] = kp[i2];
  }

  // two-step quadrant reduction of the 8 token-part partial S tiles
  if (npart < 4){
    float* pb = &lds[npart][0];
#pragma unroll
    for (int i2=0;i2<4;i2++){
      int base = (dq*4 + i2)*64 + eg*16;
      f32x4 a0; a0[0]=acc[i2][0];  a0[1]=acc[i2][1];  a0[2]=acc[i2][2];  a0[3]=acc[i2][3];
      f32x4 a1; a1[0]=acc[i2][4];  a1[1]=acc[i2][5];  a1[2]=acc[i2][6];  a1[3]=acc[i2][7];
      f32x4 a2; a2[0]=acc[i2][8];  a2[1]=acc[i2][9];  a2[2]=acc[i2][10]; a2[3]=acc[i2][11];
      f32x4 a3; a3[0]=acc[i2][12]; a3[1]=acc[i2][13]; a3[2]=acc[i2][14]; a3[3]=acc[i2][15];
      *(f32x4*)(pb + base + 0)  = a0;
      *(f32x4*)(pb + base + 4)  = a1;
      *(f32x4*)(pb + base + 8)  = a2;
      *(f32x4*)(pb + base + 12) = a3;
    }
  }
  __syncthreads();
  if (npart >= 4){
    float* pb = &lds[npart-4][0];
#pragma unroll
    for (int i2=0;i2<4;i2++){
      int base = (dq*4 + i2)*64 + eg*16;
#pragma unroll
      for (int q=0;q<4;q++){
        f32x4 cu = *(const f32x4*)(pb + base + 4*q);
        cu[0]+=acc[i2][4*q+0]; cu[1]+=acc[i2][4*q+1];
        cu[2]+=acc[i2][4*q+2]; cu[3]+=acc[i2][4*q+3];
        *(f32x4*)(pb + base + 4*q) = cu;
      }
    }
  }
  __syncthreads();

  float* outp = scoresOut + (size_t)bh*4096;
#pragma unroll
  for (int i=0;i<2;i++){
    int idx = tid + 512*i;
    int q4  = idx*4;
    int d   = idx >> 4;
    float rk = 1.0f / (ksumLds[0][d]+ksumLds[1][d]+ksumLds[2][d]+ksumLds[3][d]
                      +ksumLds[4][d]+ksumLds[5][d]+ksumLds[6][d]+ksumLds[7][d]);
    f32x4 s = *(const f32x4*)(&lds[0][q4]) + *(const f32x4*)(&lds[1][q4])
            + *(const f32x4*)(&lds[2][q4]) + *(const f32x4*)(&lds[3][q4]);
    s[0]*=rk; s[1]*=rk; s[2]*=rk; s[3]*=rk;
    *(f32x4*)(outp + q4) = s;
  }
}

// --------------------------- ctx = qn @ S ----------------------------------
// Block = (b,h, 128-token chunk).  qn read as bf16x4 (8 B per lane),
// transpose-staged to f32 LDS; register-blocked matvec.   (proven r11-r13)

__global__ __launch_bounds__(256) void k_ctx(
    const __bf16* __restrict__ t_bf, const float* __restrict__ scoresIn,
    float* __restrict__ out)
{
  __shared__ __align__(16) float S[64*64];
  __shared__ __align__(16) float qnT[64*132];

  const int tid   = threadIdx.x;
  const int bh    = blockIdx.y;
  const int b     = bh >> 4, h = bh & 15;
  const int chunk = blockIdx.x;             // 0..7
  const __bf16* qbase = t_bf + (size_t)b*1048576u + h*64;

#pragma unroll
  for (int i=0;i<4;i++){
    int q4 = (tid + 256*i)*4;
    *(f32x4*)(S + q4) = *(const f32x4*)(scoresIn + (size_t)bh*4096 + q4);
  }

  const int lane = tid & 63, w = tid >> 6;
  const int pos = lane & 15, rq = lane >> 4;
#pragma unroll
  for (int p=0;p<8;p++){
    int nl = w*32 + p*4 + rq;
    int n  = chunk*128 + nl;
    bf16x4 qv = *(const bf16x4*)(qbase + (size_t)n*1024 + pos*4);
    qnT[(pos*4+0)*132 + nl] = (float)qv[0];
    qnT[(pos*4+1)*132 + nl] = (float)qv[1];
    qnT[(pos*4+2)*132 + nl] = (float)qv[2];
    qnT[(pos*4+3)*132 + nl] = (float)qv[3];
  }
  __syncthreads();

  const int eq = tid & 15, tg = tid >> 4;
  float acc[8][4] = {};
  for (int d=0; d<64; ++d){
    f32x4 s4 = *(const f32x4*)(S   + d*64  + eq*4);
    f32x4 q0 = *(const f32x4*)(qnT + d*132 + tg*8 + 0);
    f32x4 q1 = *(const f32x4*)(qnT + d*132 + tg*8 + 4);
#pragma unroll
    for (int j=0;j<4;j++){
      acc[0][j] += q0[0]*s4[j];
      acc[1][j] += q0[1]*s4[j];
      acc[2][j] += q0[2]*s4[j];
      acc[3][j] += q0[3]*s4[j];
      acc[4][j] += q1[0]*s4[j];
      acc[5][j] += q1[1]*s4[j];
      acc[6][j] += q1[2]*s4[j];
      acc[7][j] += q1[3]*s4[j];
    }
  }
#pragma unroll
  for (int i2=0;i2<8;i2++){
    int n = chunk*128 + tg*8 + i2;
    f32x4 o; o[0]=acc[i2][0]; o[1]=acc[i2][1]; o[2]=acc[i2][2]; o[3]=acc[i2][3];
    *(f32x4*)(out + (size_t)(b*1024 + n)*1024 + h*64 + eq*4) = o;
  }
}

// --------------------------- launcher --------------------------------------

extern "C" void kernel_launch(void* const* d_in, const int* in_sizes, int n_in,
                              void* d_out, int out_size, void* d_ws, size_t ws_size,
                              hipStream_t stream)
{
  const float* q_img = (const float*)d_in[0];
  const float* k_img = (const float*)d_in[1];
  const float* v_img = (const float*)d_in[2];
  const float* wq    = (const float*)d_in[3];
  const float* bq    = (const float*)d_in[4];
  const float* wk    = (const float*)d_in[5];
  const float* bk    = (const float*)d_in[6];
  const float* wv    = (const float*)d_in[7];
  const float* bv    = (const float*)d_in[8];
  float* out = (float*)d_out;
  char*  ws  = (char*)d_ws;

  unsigned short* t_bf   = (unsigned short*)ws;             // 96 MiB
  unsigned short* wbf    = (unsigned short*)(ws + 0x6000000);
  float*          pe     = (float*)(ws + 0x6480000);
  float*          scores = (float*)(ws + 0x6880000);
  unsigned short* x_bf   = (unsigned short*)(ws + 0x6C80000);  // 72 MiB

  k_prep_w <<<dim3(2304),  dim3(256), 0, stream>>>(wq, wk, wv, wbf);
  k_prep_pe<<<dim3(4096),  dim3(256), 0, stream>>>(pe);
  k_prep_x <<<dim3(18432), dim3(256), 0, stream>>>(q_img, k_img, v_img, x_bf);
  k_embed  <<<dim3(8,128,3), dim3(256), 0, stream>>>(x_bf, wbf,
                                                     bq,bk,bv, pe, t_bf);
  k_scores <<<dim3(256),  dim3(512), 0, stream>>>((const __bf16*)t_bf, scores);
  k_ctx    <<<dim3(8,256), dim3(256), 0, stream>>>((const __bf16*)t_bf, scores, out);
}

// Round 15
// 243.913 us; speedup vs baseline: 1.1251x; 1.1251x over previous
//
#include <hip/hip_runtime.h>
#include <hip/hip_bf16.h>

// ---------------------------------------------------------------------------
// VisionLinearAttention: x->bf16 prep, patch-embed (all-bf16 MFMA GEMM with
// fused bias+PE+softmax epilogue, bf16 outputs) -> scores = ek^T v ->
// ctx = qn @ S.
//
// Shapes: B=16, C=3, H=W=512, PATCH=16 -> N=1024 tokens, D=1024, K=768,
//         heads=16, hd=64.  M = B*N = 16384.
//
// t-region semantics after k_embed (ALL bf16):
//   z=0: qn  = softmax over head_dim of (q+bias+pe)   in [0,1]
//   z=1: ek  = exp(k+bias+pe)                          <= ~67
//   z=2: v   = v+bias+pe                               ~ +-5
//
// Workspace map (bytes):
//   0x0000000  t_bf[3][16384][1024] bf16  96 MiB
//   0x6000000  wbf[3][1024][768]  bf16    4.5 MiB
//   0x6480000  pe[1024][1024] f32         4 MiB
//   0x6880000  scores[256][64][64] f32    4 MiB
//   0x6C80000  x_bf[3][12582912] bf16     72 MiB
//
// Ledger: R13 (125us embed) validated the L2 model (3 blocks/CU -> 12
// resident A-panels = 3.85MB < 4MB L2 -> FETCH 135MB).  R14's counted-vmcnt
// dbuf lost occupancy (2 blocks) and regressed.  R15 keeps R13's skeleton
// and L2 footprint but runs 8 waves/block (512 thr, 4m x 2n wave layout):
// 24 waves/CU (Occ ~75%) for latency hiding, same 3 blocks/CU.
// ---------------------------------------------------------------------------

typedef float  f32x4  __attribute__((ext_vector_type(4)));
typedef __bf16 bf16x8 __attribute__((ext_vector_type(8)));
typedef __bf16 bf16x4 __attribute__((ext_vector_type(4)));

#define LN10000 9.210340371976184f

__device__ __forceinline__ unsigned short f2bf_bits(float f){
  union { float f; unsigned u; } a; a.f = f;
  unsigned r = a.u + 0x7FFFu + ((a.u >> 16) & 1u);   // round-to-nearest-even
  return (unsigned short)(r >> 16);
}

__device__ __forceinline__ void gload16(const void* g, void* l){
  __builtin_amdgcn_global_load_lds((__attribute__((address_space(1))) void*)g,
                                   (__attribute__((address_space(3))) void*)l,
                                   16, 0, 0);
}

// --------------------------- prep kernels ----------------------------------

__global__ __launch_bounds__(256) void k_prep_w(
    const float* __restrict__ wq, const float* __restrict__ wk,
    const float* __restrict__ wv, unsigned short* __restrict__ wbf)
{
  int i = blockIdx.x*256 + threadIdx.x;      // quad index, 3*786432/4 = 589824
  if (i >= 589824) return;
  int z = i / 196608;
  int r = i - z*196608;
  const float* src = (z==0) ? wq : (z==1 ? wk : wv);
  f32x4 v = ((const f32x4*)src)[r];
  unsigned lo = (unsigned)f2bf_bits(v[0]) | ((unsigned)f2bf_bits(v[1]) << 16);
  unsigned hh = (unsigned)f2bf_bits(v[2]) | ((unsigned)f2bf_bits(v[3]) << 16);
  ((uint2*)wbf)[i] = make_uint2(lo, hh);
}

__global__ __launch_bounds__(256) void k_prep_pe(float* __restrict__ pe)
{
  int i = blockIdx.x*256 + threadIdx.x;      // 1024*1024
  if (i >= 1048576) return;
  int n = i >> 10, dd = i & 1023;
  float ex  = (float)(dd & ~1) * (1.0f/1024.0f);
  float ang = (float)n * expf(-LN10000 * ex);
  pe[i] = (dd & 1) ? cosf(ang) : sinf(ang);
}

// x (3 images, f32) -> bf16, flat same layout.  8 elems / thread.
__global__ __launch_bounds__(256) void k_prep_x(
    const float* __restrict__ xq, const float* __restrict__ xk,
    const float* __restrict__ xv, unsigned short* __restrict__ x_bf)
{
  int i = blockIdx.x*256 + threadIdx.x;      // 8-elem unit; 4718592 total
  if (i >= 4718592) return;
  int z = i / 1572864;
  int r = i - z*1572864;
  const float* src = (z==0) ? xq : (z==1 ? xk : xv);
  f32x4 a = ((const f32x4*)src)[r*2];
  f32x4 b = ((const f32x4*)src)[r*2+1];
  uint4 o;
  o.x = (unsigned)f2bf_bits(a[0]) | ((unsigned)f2bf_bits(a[1]) << 16);
  o.y = (unsigned)f2bf_bits(a[2]) | ((unsigned)f2bf_bits(a[3]) << 16);
  o.z = (unsigned)f2bf_bits(b[0]) | ((unsigned)f2bf_bits(b[1]) << 16);
  o.w = (unsigned)f2bf_bits(b[2]) | ((unsigned)f2bf_bits(b[3]) << 16);
  ((uint4*)x_bf)[i] = o;
}

// --------------------------- patch-embed GEMM ------------------------------
// 128x128 tile, BK=64, 8 waves (4m x 2n; wave = 32x64 output, acc[2][4]),
// mfma 16x16x32.  R13's proven 2-barrier __syncthreads skeleton, all-bf16
// gload_lds staging (both operands, 128 B rows, XOR swizzle both sides),
// XCD swizzle, fused epilogue.  LDS 32 KiB + 16 KiB pad = 48 KiB ->
// 3 blocks/CU (R13's validated L2 regime) x 8 waves = 24 waves/CU.

__global__ __launch_bounds__(512, 5) void k_embed(
    const unsigned short* __restrict__ x_bf,
    const unsigned short* __restrict__ wbf,
    const float* __restrict__ bq, const float* __restrict__ bk,
    const float* __restrict__ bv, const float* __restrict__ pe,
    unsigned short* __restrict__ t_bf)
{
  __shared__ __align__(16) unsigned short ldsA[128*64];   // 16 KiB bf16
  __shared__ __align__(16) unsigned short ldsB[128*64];   // 16 KiB bf16
  __shared__ __align__(16) float ldsPad[4096];            // 16 KiB occupancy cap

  const int tid = threadIdx.x;                 // 0..511
  // XCD swizzle: orig tile id = (flat&7)*384 + (flat>>3).  3072 = 8*384,
  // 384%8==0, so each m-tile's 8 consecutive d-tiles share flat&7 (one XCD).
  int flat = blockIdx.x + (blockIdx.y << 3) + (blockIdx.z << 10); // 0..3071
  int orig = (flat & 7)*384 + (flat >> 3);
  const int z   = orig >> 10;
  const int rem = orig & 1023;
  const int m0  = (rem >> 3) * 128;
  const int d0  = (rem & 7) * 128;

  const unsigned short* xbz = x_bf + (size_t)z*12582912u;
  const unsigned short* wz  = wbf + z*786432;
  const float* bias = (z==0) ? bq : (z==1 ? bk : bv);
  unsigned short* tout = t_bf + (size_t)z*16777216u;

  // keep ldsPad allocated: data-dependent never-true guard (bias is ~0.02)
  if (bias[0] > 1.0e30f){
    ldsPad[tid] = pe[tid];
    __syncthreads();
    tout[tid] = f2bf_bits(ldsPad[511 - (tid & 511)]);
  }

  // ---- A staging map: dest byte L = i*8192 + tid*16, 128 B rows, 2 loads.
  // aKK = bf16 element offset within the 64-wide k-slice (multiple of 8).
  int aRowG[2], aKK[2];
#pragma unroll
  for (int i=0;i<2;i++){
    int L   = i*8192 + tid*16;
    int row = L >> 7;                   // 0..127
    int U   = L ^ ((row & 7) << 4);     // inverse-swizzled source slot
    aKK[i]  = (U & 127) >> 1;
    int m   = m0 + row;
    int bimg = m >> 10, nt = m & 1023;
    aRowG[i] = bimg*786432 + (nt>>5)*8192 + (nt&31)*16;
  }
  // ---- B staging map: identical structure ----
  int bOff[2];
#pragma unroll
  for (int i=0;i<2;i++){
    int L   = i*8192 + tid*16;
    int row = L >> 7;
    int U   = L ^ ((row & 7) << 4);
    bOff[i] = (d0 + row)*768 + ((U >> 1) & 63);
  }

  const int lane = tid & 63;
  const int wid  = tid >> 6;              // 0..7
  const int ln   = lane & 15, hi4 = lane >> 4;
  const int wm   = wid >> 1,  wn  = wid & 1;   // wm 0..3 (32-row strips), wn 0..1

  f32x4 acc[2][4] = {};
  char* ldsAc = (char*)ldsA;
  char* ldsBc = (char*)ldsB;

  for (int ks=0; ks<12; ++ks){
#pragma unroll
    for (int i=0;i<2;i++){
      int k   = ks*64 + aKK[i];
      int c   = k >> 8, r2 = k & 255;
      gload16(xbz + aRowG[i] + c*262144 + (r2>>4)*512 + (r2 & 15),
              ldsAc + i*8192 + wid*1024);
    }
#pragma unroll
    for (int i=0;i<2;i++){
      gload16(wz + bOff[i] + ks*64, ldsBc + i*8192 + wid*1024);
    }
    __syncthreads();

#pragma unroll
    for (int kc=0; kc<2; ++kc){
      bf16x8 af[2], bfr[4];
#pragma unroll
      for (int mi=0;mi<2;mi++){
        int row  = wm*32 + mi*16 + ln;
        int byte = (row*128 + kc*64 + hi4*16) ^ ((row & 7) << 4);
        af[mi] = *(const bf16x8*)(ldsAc + byte);
      }
#pragma unroll
      for (int ni=0;ni<4;ni++){
        int row  = wn*64 + ni*16 + ln;
        int byte = (row*128 + kc*64 + hi4*16) ^ ((row & 7) << 4);
        bfr[ni] = *(const bf16x8*)(ldsBc + byte);
      }
#pragma unroll
      for (int mi=0;mi<2;mi++)
#pragma unroll
        for (int ni=0;ni<4;ni++)
          acc[mi][ni] = __builtin_amdgcn_mfma_f32_16x16x32_bf16(
              af[mi], bfr[ni], acc[mi][ni], 0, 0, 0);
    }
    __syncthreads();
  }

  // ---- fused epilogue: + bias + PE, per-tensor transform, bf16 store ----
  // This wave's 64 output cols = exactly one head (d0 + wn*64 .. +63).
  float bias4[4];
#pragma unroll
  for (int ni=0;ni<4;ni++) bias4[ni] = bias[d0 + wn*64 + ni*16 + ln];

#pragma unroll
  for (int mi=0;mi<2;mi++){
#pragma unroll
    for (int r=0;r<4;r++){
      int m    = m0 + wm*32 + mi*16 + hi4*4 + r;
      int ntok = m & 1023;
      float vv[4];
#pragma unroll
      for (int ni=0;ni<4;ni++){
        int dd = d0 + wn*64 + ni*16 + ln;
        vv[ni] = acc[mi][ni][r] + bias4[ni] + pe[ntok*1024 + dd];
      }
      size_t base = (size_t)m*1024 + d0 + wn*64 + ln;
      if (z == 0){
        // softmax over the 64-dim head: 4 per-thread + 16-lane shfl group
        // (the 16-lane group = contiguous lanes sharing hi4 -> same row m)
        float ex0=__expf(vv[0]), ex1=__expf(vv[1]),
              ex2=__expf(vv[2]), ex3=__expf(vv[3]);
        float ps = ex0+ex1+ex2+ex3;
        ps += __shfl_xor(ps, 1); ps += __shfl_xor(ps, 2);
        ps += __shfl_xor(ps, 4); ps += __shfl_xor(ps, 8);
        float w = 1.0f / ps;
        tout[base +  0] = f2bf_bits(ex0*w);  tout[base + 16] = f2bf_bits(ex1*w);
        tout[base + 32] = f2bf_bits(ex2*w);  tout[base + 48] = f2bf_bits(ex3*w);
      } else if (z == 1){
        tout[base +  0] = f2bf_bits(__expf(vv[0]));
        tout[base + 16] = f2bf_bits(__expf(vv[1]));
        tout[base + 32] = f2bf_bits(__expf(vv[2]));
        tout[base + 48] = f2bf_bits(__expf(vv[3]));
      } else {
        tout[base +  0] = f2bf_bits(vv[0]); tout[base + 16] = f2bf_bits(vv[1]);
        tout[base + 32] = f2bf_bits(vv[2]); tout[base + 48] = f2bf_bits(vv[3]);
      }
    }
  }
}

// --------------------------- scores = ek^T v -------------------------------
// One block (512 threads = 16 waves) per (b,h).  ek,v read as bf16 (16 B
// per lane), converted to f32 in LDS.  Proven 2-phase dbuf skeleton over 16
// chunks of 64 tokens; npart in [0,8) splits tokens; two-step quadrant
// reduction; ksum folded; S stored normalized f32.   (proven r11-r14)

__global__ __launch_bounds__(512) void k_scores(
    const __bf16* __restrict__ t_bf, float* __restrict__ scoresOut)
{
  __shared__ __align__(16) float lds[4][4096];  // [0],[1]=ek dbuf; [2],[3]=v dbuf
  __shared__ float ksumLds[8][64];

  const int tid = threadIdx.x;                // 0..511
  const int bh  = blockIdx.x;
  const int b   = bh >> 4, h = bh & 15;
  const __bf16* kbase = t_bf + 16777216u + (size_t)b*1048576u + h*64;
  const __bf16* vbase = t_bf + 33554432u + (size_t)b*1048576u + h*64;

  const int dq = tid & 15, eg = (tid>>4) & 3, npart = tid >> 6;  // npart 0..7
  const int srow = tid >> 3;        // 0..63 (stage row; 8 threads/row)
  const int dcol = (tid & 7) * 8;   // bf16 elem col within the 64-dim slice

#define STAGE(BUF, CH) do{                                                \
    size_t g = (size_t)((CH)*64 + srow)*1024 + dcol;                      \
    bf16x8 k8 = *(const bf16x8*)(kbase + g);                              \
    bf16x8 v8 = *(const bf16x8*)(vbase + g);                              \
    f32x4 e0, e1, w0, w1;                                                 \
    e0[0]=(float)k8[0]; e0[1]=(float)k8[1]; e0[2]=(float)k8[2]; e0[3]=(float)k8[3]; \
    e1[0]=(float)k8[4]; e1[1]=(float)k8[5]; e1[2]=(float)k8[6]; e1[3]=(float)k8[7]; \
    w0[0]=(float)v8[0]; w0[1]=(float)v8[1]; w0[2]=(float)v8[2]; w0[3]=(float)v8[3]; \
    w1[0]=(float)v8[4]; w1[1]=(float)v8[5]; w1[2]=(float)v8[6]; w1[3]=(float)v8[7]; \
    *(f32x4*)(&lds[BUF][srow*64 + dcol])       = e0;                      \
    *(f32x4*)(&lds[BUF][srow*64 + dcol + 4])   = e1;                      \
    *(f32x4*)(&lds[2+(BUF)][srow*64 + dcol])     = w0;                    \
    *(f32x4*)(&lds[2+(BUF)][srow*64 + dcol + 4]) = w1;                    \
  }while(0)

  float acc[4][16] = {};
  float kp[4] = {0.f,0.f,0.f,0.f};

  STAGE(0, 0);
  __syncthreads();
  for (int ch=0; ch<16; ++ch){
    int cur = ch & 1;
    if (ch < 15) STAGE(cur^1, ch+1);   // writes OTHER buffer: safe vs compute
    for (int nn = npart; nn < 64; nn += 8){
      f32x4 ek4 = *(const f32x4*)(&lds[cur][nn*64 + dq*4]);
      f32x4 v0  = *(const f32x4*)(&lds[2+cur][nn*64 + eg*16 + 0]);
      f32x4 v1  = *(const f32x4*)(&lds[2+cur][nn*64 + eg*16 + 4]);
      f32x4 v2  = *(const f32x4*)(&lds[2+cur][nn*64 + eg*16 + 8]);
      f32x4 v3  = *(const f32x4*)(&lds[2+cur][nn*64 + eg*16 + 12]);
#pragma unroll
      for (int i2=0;i2<4;i2++){
        kp[i2] += ek4[i2];
#pragma unroll
        for (int j=0;j<4;j++){
          acc[i2][j+0]  += ek4[i2]*v0[j];
          acc[i2][j+4]  += ek4[i2]*v1[j];
          acc[i2][j+8]  += ek4[i2]*v2[j];
          acc[i2][j+12] += ek4[i2]*v3[j];
        }
      }
    }
    __syncthreads();
  }
#undef STAGE

  // kp identical across the 16 eg threads of a (dq,npart); eg==0 publishes.
  if (eg == 0){
#pragma unroll
    for (int i2=0;i2<4;i2++) ksumLds[npart][dq*4 + i2] = kp[i2];
  }

  // two-step quadrant reduction of the 8 token-part partial S tiles
  if (npart < 4){
    float* pb = &lds[npart][0];
#pragma unroll
    for (int i2=0;i2<4;i2++){
      int base = (dq*4 + i2)*64 + eg*16;
      f32x4 a0; a0[0]=acc[i2][0];  a0[1]=acc[i2][1];  a0[2]=acc[i2][2];  a0[3]=acc[i2][3];
      f32x4 a1; a1[0]=acc[i2][4];  a1[1]=acc[i2][5];  a1[2]=acc[i2][6];  a1[3]=acc[i2][7];
      f32x4 a2; a2[0]=acc[i2][8];  a2[1]=acc[i2][9];  a2[2]=acc[i2][10]; a2[3]=acc[i2][11];
      f32x4 a3; a3[0]=acc[i2][12]; a3[1]=acc[i2][13]; a3[2]=acc[i2][14]; a3[3]=acc[i2][15];
      *(f32x4*)(pb + base + 0)  = a0;
      *(f32x4*)(pb + base + 4)  = a1;
      *(f32x4*)(pb + base + 8)  = a2;
      *(f32x4*)(pb + base + 12) = a3;
    }
  }
  __syncthreads();
  if (npart >= 4){
    float* pb = &lds[npart-4][0];
#pragma unroll
    for (int i2=0;i2<4;i2++){
      int base = (dq*4 + i2)*64 + eg*16;
#pragma unroll
      for (int q=0;q<4;q++){
        f32x4 cu = *(const f32x4*)(pb + base + 4*q);
        cu[0]+=acc[i2][4*q+0]; cu[1]+=acc[i2][4*q+1];
        cu[2]+=acc[i2][4*q+2]; cu[3]+=acc[i2][4*q+3];
        *(f32x4*)(pb + base + 4*q) = cu;
      }
    }
  }
  __syncthreads();

  float* outp = scoresOut + (size_t)bh*4096;
#pragma unroll
  for (int i=0;i<2;i++){
    int idx = tid + 512*i;
    int q4  = idx*4;
    int d   = idx >> 4;
    float rk = 1.0f / (ksumLds[0][d]+ksumLds[1][d]+ksumLds[2][d]+ksumLds[3][d]
                      +ksumLds[4][d]+ksumLds[5][d]+ksumLds[6][d]+ksumLds[7][d]);
    f32x4 s = *(const f32x4*)(&lds[0][q4]) + *(const f32x4*)(&lds[1][q4])
            + *(const f32x4*)(&lds[2][q4]) + *(const f32x4*)(&lds[3][q4]);
    s[0]*=rk; s[1]*=rk; s[2]*=rk; s[3]*=rk;
    *(f32x4*)(outp + q4) = s;
  }
}

// --------------------------- ctx = qn @ S ----------------------------------
// Block = (b,h, 128-token chunk).  qn read as bf16x4 (8 B per lane),
// transpose-staged to f32 LDS; register-blocked matvec.   (proven r11-r14)

__global__ __launch_bounds__(256) void k_ctx(
    const __bf16* __restrict__ t_bf, const float* __restrict__ scoresIn,
    float* __restrict__ out)
{
  __shared__ __align__(16) float S[64*64];
  __shared__ __align__(16) float qnT[64*132];

  const int tid   = threadIdx.x;
  const int bh    = blockIdx.y;
  const int b     = bh >> 4, h = bh & 15;
  const int chunk = blockIdx.x;             // 0..7
  const __bf16* qbase = t_bf + (size_t)b*1048576u + h*64;

#pragma unroll
  for (int i=0;i<4;i++){
    int q4 = (tid + 256*i)*4;
    *(f32x4*)(S + q4) = *(const f32x4*)(scoresIn + (size_t)bh*4096 + q4);
  }

  const int lane = tid & 63, w = tid >> 6;
  const int pos = lane & 15, rq = lane >> 4;
#pragma unroll
  for (int p=0;p<8;p++){
    int nl = w*32 + p*4 + rq;
    int n  = chunk*128 + nl;
    bf16x4 qv = *(const bf16x4*)(qbase + (size_t)n*1024 + pos*4);
    qnT[(pos*4+0)*132 + nl] = (float)qv[0];
    qnT[(pos*4+1)*132 + nl] = (float)qv[1];
    qnT[(pos*4+2)*132 + nl] = (float)qv[2];
    qnT[(pos*4+3)*132 + nl] = (float)qv[3];
  }
  __syncthreads();

  const int eq = tid & 15, tg = tid >> 4;
  float acc[8][4] = {};
  for (int d=0; d<64; ++d){
    f32x4 s4 = *(const f32x4*)(S   + d*64  + eq*4);
    f32x4 q0 = *(const f32x4*)(qnT + d*132 + tg*8 + 0);
    f32x4 q1 = *(const f32x4*)(qnT + d*132 + tg*8 + 4);
#pragma unroll
    for (int j=0;j<4;j++){
      acc[0][j] += q0[0]*s4[j];
      acc[1][j] += q0[1]*s4[j];
      acc[2][j] += q0[2]*s4[j];
      acc[3][j] += q0[3]*s4[j];
      acc[4][j] += q1[0]*s4[j];
      acc[5][j] += q1[1]*s4[j];
      acc[6][j] += q1[2]*s4[j];
      acc[7][j] += q1[3]*s4[j];
    }
  }
#pragma unroll
  for (int i2=0;i2<8;i2++){
    int n = chunk*128 + tg*8 + i2;
    f32x4 o; o[0]=acc[i2][0]; o[1]=acc[i2][1]; o[2]=acc[i2][2]; o[3]=acc[i2][3];
    *(f32x4*)(out + (size_t)(b*1024 + n)*1024 + h*64 + eq*4) = o;
  }
}

// --------------------------- launcher --------------------------------------

extern "C" void kernel_launch(void* const* d_in, const int* in_sizes, int n_in,
                              void* d_out, int out_size, void* d_ws, size_t ws_size,
                              hipStream_t stream)
{
  const float* q_img = (const float*)d_in[0];
  const float* k_img = (const float*)d_in[1];
  const float* v_img = (const float*)d_in[2];
  const float* wq    = (const float*)d_in[3];
  const float* bq    = (const float*)d_in[4];
  const float* wk    = (const float*)d_in[5];
  const float* bk    = (const float*)d_in[6];
  const float* wv    = (const float*)d_in[7];
  const float* bv    = (const float*)d_in[8];
  float* out = (float*)d_out;
  char*  ws  = (char*)d_ws;

  unsigned short* t_bf   = (unsigned short*)ws;             // 96 MiB
  unsigned short* wbf    = (unsigned short*)(ws + 0x6000000);
  float*          pe     = (float*)(ws + 0x6480000);
  float*          scores = (float*)(ws + 0x6880000);
  unsigned short* x_bf   = (unsigned short*)(ws + 0x6C80000);  // 72 MiB

  k_prep_w <<<dim3(2304),  dim3(256), 0, stream>>>(wq, wk, wv, wbf);
  k_prep_pe<<<dim3(4096),  dim3(256), 0, stream>>>(pe);
  k_prep_x <<<dim3(18432), dim3(256), 0, stream>>>(q_img, k_img, v_img, x_bf);
  k_embed  <<<dim3(8,128,3), dim3(512), 0, stream>>>(x_bf, wbf,
                                                     bq,bk,bv, pe, t_bf);
  k_scores <<<dim3(256),  dim3(512), 0, stream>>>((const __bf16*)t_bf, scores);
  k_ctx    <<<dim3(8,256), dim3(256), 0, stream>>>((const __bf16*)t_bf, scores, out);
}

// Round 16
// 237.380 us; speedup vs baseline: 1.1560x; 1.0275x over previous
//
#include <hip/hip_runtime.h>
#include <hip/hip_bf16.h>

// ---------------------------------------------------------------------------
// VisionLinearAttention: merged prep (w->bf16, pe table, x->bf16), patch-embed
// (all-bf16 MFMA GEMM, counted-vmcnt double-buffer, fused bias+PE+softmax
// epilogue, bf16 outputs) -> scores = ek^T v -> ctx = qn @ S.
//
// Shapes: B=16, C=3, H=W=512, PATCH=16 -> N=1024 tokens, D=1024, K=768,
//         heads=16, hd=64.  M = B*N = 16384.
//
// t-region semantics after k_embed (ALL bf16):
//   z=0: qn  = softmax over head_dim of (q+bias+pe)   in [0,1]
//   z=1: ek  = exp(k+bias+pe)                          <= ~67
//   z=2: v   = v+bias+pe                               ~ +-5
//
// Workspace map (bytes):
//   0x0000000  t_bf[3][16384][1024] bf16  96 MiB
//   0x6000000  wbf[3][1024][768]  bf16    4.5 MiB
//   0x6480000  pe[1024][1024] f32         4 MiB
//   0x6880000  scores[256][64][64] f32    4 MiB
//   0x6C80000  x_bf[3][12582912] bf16     72 MiB
//
// Ledger: R13/R15 fixed the L2 regime (3 blocks/CU -> 12 resident A-panels
// < 4MB L2).  R15 showed embed is NOT occupancy-bound (Occ 40% = same dur);
// it's in-block serialized on the per-K-step load drain.  R16 = R8's proven
// counted-vmcnt dbuf skeleton at BK=32 bf16: 32KB dbuf + 16KB pad = 48KB
// keeps 3 blocks/CU (same L2 residency) while loads land one K-step early.
// ---------------------------------------------------------------------------

typedef float  f32x4  __attribute__((ext_vector_type(4)));
typedef __bf16 bf16x8 __attribute__((ext_vector_type(8)));
typedef __bf16 bf16x4 __attribute__((ext_vector_type(4)));

#define LN10000 9.210340371976184f

__device__ __forceinline__ unsigned short f2bf_bits(float f){
  union { float f; unsigned u; } a; a.f = f;
  unsigned r = a.u + 0x7FFFu + ((a.u >> 16) & 1u);   // round-to-nearest-even
  return (unsigned short)(r >> 16);
}

__device__ __forceinline__ void gload16(const void* g, void* l){
  __builtin_amdgcn_global_load_lds((__attribute__((address_space(1))) void*)g,
                                   (__attribute__((address_space(3))) void*)l,
                                   16, 0, 0);
}

// --------------------------- merged prep kernel ----------------------------
// blocks [0,2304)        : w -> bf16     (589824 quads)
// blocks [2304,6400)     : pe table      (1048576 elems)
// blocks [6400,24832)    : x -> bf16     (4718592 8-elem units)

__global__ __launch_bounds__(256) void k_prep_all(
    const float* __restrict__ wq, const float* __restrict__ wk,
    const float* __restrict__ wv, unsigned short* __restrict__ wbf,
    float* __restrict__ pe,
    const float* __restrict__ xq, const float* __restrict__ xk,
    const float* __restrict__ xv, unsigned short* __restrict__ x_bf)
{
  int bid = blockIdx.x;
  if (bid < 2304){
    int i = bid*256 + threadIdx.x;
    if (i >= 589824) return;
    int z = i / 196608;
    int r = i - z*196608;
    const float* src = (z==0) ? wq : (z==1 ? wk : wv);
    f32x4 v = ((const f32x4*)src)[r];
    unsigned lo = (unsigned)f2bf_bits(v[0]) | ((unsigned)f2bf_bits(v[1]) << 16);
    unsigned hh = (unsigned)f2bf_bits(v[2]) | ((unsigned)f2bf_bits(v[3]) << 16);
    ((uint2*)wbf)[i] = make_uint2(lo, hh);
  } else if (bid < 6400){
    int i = (bid - 2304)*256 + threadIdx.x;
    if (i >= 1048576) return;
    int n = i >> 10, dd = i & 1023;
    float ex  = (float)(dd & ~1) * (1.0f/1024.0f);
    float ang = (float)n * expf(-LN10000 * ex);
    pe[i] = (dd & 1) ? cosf(ang) : sinf(ang);
  } else {
    int i = (bid - 6400)*256 + threadIdx.x;
    if (i >= 4718592) return;
    int z = i / 1572864;
    int r = i - z*1572864;
    const float* src = (z==0) ? xq : (z==1 ? xk : xv);
    f32x4 a = ((const f32x4*)src)[r*2];
    f32x4 b = ((const f32x4*)src)[r*2+1];
    uint4 o;
    o.x = (unsigned)f2bf_bits(a[0]) | ((unsigned)f2bf_bits(a[1]) << 16);
    o.y = (unsigned)f2bf_bits(a[2]) | ((unsigned)f2bf_bits(a[3]) << 16);
    o.z = (unsigned)f2bf_bits(b[0]) | ((unsigned)f2bf_bits(b[1]) << 16);
    o.w = (unsigned)f2bf_bits(b[2]) | ((unsigned)f2bf_bits(b[3]) << 16);
    ((uint4*)x_bf)[i] = o;
  }
}

// --------------------------- patch-embed GEMM ------------------------------
// 128x128 tile, BK=32, 4 waves (2x2), 4x4 mfma 16x16x32 per K-step (K=32
// consumed in one mfma per (mi,ni)).  All-bf16 gload_lds staging, 64 B LDS
// rows, XOR swizzle (row&3)<<4 both sides.  COUNTED-VMCNT DOUBLE-BUFFER
// (R8's proven skeleton):
//   iter ks: STAGE(buf^1, ks+1) [4 loads]; s_waitcnt vmcnt(4) (cur landed);
//            sched_barrier; s_barrier; sched_barrier;
//            ds_read + 16 MFMA from buf[cur];
//            sched_barrier; s_barrier.
// Hazards: stale-read covered by vmcnt(4)+barrier#1; WAR by barrier#2;
// uniform control flow.  LDS 32 KiB dbuf + 16 KiB pad = 48 KiB ->
// 3 blocks/CU (R13/R15-validated L2 residency; FETCH must stay ~172 MB).

__global__ __launch_bounds__(256, 3) void k_embed(
    const unsigned short* __restrict__ x_bf,
    const unsigned short* __restrict__ wbf,
    const float* __restrict__ bq, const float* __restrict__ bk,
    const float* __restrict__ bv, const float* __restrict__ pe,
    unsigned short* __restrict__ t_bf)
{
  __shared__ __align__(16) unsigned short ldsA[2][128*32];   // 2 x 8 KiB
  __shared__ __align__(16) unsigned short ldsB[2][128*32];   // 2 x 8 KiB
  __shared__ __align__(16) float ldsPad[4096];               // 16 KiB occ cap

  const int tid = threadIdx.x;
  // XCD swizzle: orig tile id = (flat&7)*384 + (flat>>3).  3072 = 8*384,
  // 384%8==0, so each m-tile's 8 consecutive d-tiles share flat&7 (one XCD).
  int flat = blockIdx.x + (blockIdx.y << 3) + (blockIdx.z << 10); // 0..3071
  int orig = (flat & 7)*384 + (flat >> 3);
  const int z   = orig >> 10;
  const int rem = orig & 1023;
  const int m0  = (rem >> 3) * 128;
  const int d0  = (rem & 7) * 128;

  const unsigned short* xbz = x_bf + (size_t)z*12582912u;
  const unsigned short* wz  = wbf + z*786432;
  const float* bias = (z==0) ? bq : (z==1 ? bk : bv);
  unsigned short* tout = t_bf + (size_t)z*16777216u;

  // keep ldsPad allocated: data-dependent never-true guard (bias is ~0.02)
  if (bias[0] > 1.0e30f){
    ldsPad[tid] = pe[tid];
    __syncthreads();
    tout[tid] = f2bf_bits(ldsPad[255 - (tid & 255)]);
  }

  // ---- A staging map: dest byte L = i*4096 + tid*16, 64 B rows, 2 loads.
  // aKK = bf16 element offset within the 32-wide k-slice (multiple of 8).
  int aRowG[2], aKK[2];
#pragma unroll
  for (int i=0;i<2;i++){
    int L   = i*4096 + tid*16;
    int row = L >> 6;                   // 0..127 (64 B rows)
    int U   = L ^ ((row & 3) << 4);     // inverse-swizzled source slot
    aKK[i]  = (U & 63) >> 1;            // 0,8,16,24
    int m   = m0 + row;
    int bimg = m >> 10, nt = m & 1023;
    aRowG[i] = bimg*786432 + (nt>>5)*8192 + (nt&31)*16;
  }
  // ---- B staging map: identical structure ----
  int bOff[2];
#pragma unroll
  for (int i=0;i<2;i++){
    int L   = i*4096 + tid*16;
    int row = L >> 6;
    int U   = L ^ ((row & 3) << 4);
    bOff[i] = (d0 + row)*768 + ((U & 63) >> 1);
  }

  const int lane = tid & 63;
  const int wid  = tid >> 6;
  const int ln   = lane & 15, hi4 = lane >> 4;
  const int wm   = wid >> 1,  wn  = wid & 1;

  f32x4 acc[4][4] = {};

#define STAGE(BUF, KS) do{                                                  \
    _Pragma("unroll")                                                       \
    for (int i=0;i<2;i++){                                                  \
      int k  = (KS)*32 + aKK[i];                                            \
      int c  = k >> 8, r2 = k & 255;                                        \
      gload16(xbz + aRowG[i] + c*262144 + (r2>>4)*512 + (r2 & 15),          \
              (char*)(&ldsA[BUF][0]) + i*4096 + wid*1024);                  \
    }                                                                       \
    _Pragma("unroll")                                                       \
    for (int i=0;i<2;i++){                                                  \
      gload16(wz + bOff[i] + (KS)*32,                                       \
              (char*)(&ldsB[BUF][0]) + i*4096 + wid*1024);                  \
    } }while(0)

  STAGE(0, 0);
  for (int ks=0; ks<24; ++ks){
    int cur = ks & 1;
    if (ks < 23){
      STAGE(cur^1, ks+1);               // 4 async loads into OTHER buffer
      asm volatile("s_waitcnt vmcnt(4)" ::: "memory");  // cur's 4 landed
    } else {
      asm volatile("s_waitcnt vmcnt(0)" ::: "memory");
    }
    __builtin_amdgcn_sched_barrier(0);
    __builtin_amdgcn_s_barrier();       // all waves: cur staged
    __builtin_amdgcn_sched_barrier(0);

    const char* pA = (const char*)&ldsA[cur][0];
    const char* pB = (const char*)&ldsB[cur][0];
    bf16x8 af[4], bfr[4];
#pragma unroll
    for (int mi=0;mi<4;mi++){
      int row  = wm*64 + mi*16 + ln;
      int byte = (row*64 + hi4*16) ^ ((row & 3) << 4);
      af[mi] = *(const bf16x8*)(pA + byte);
    }
#pragma unroll
    for (int ni=0;ni<4;ni++){
      int row  = wn*64 + ni*16 + ln;
      int byte = (row*64 + hi4*16) ^ ((row & 3) << 4);
      bfr[ni] = *(const bf16x8*)(pB + byte);
    }
#pragma unroll
    for (int mi=0;mi<4;mi++)
#pragma unroll
      for (int ni=0;ni<4;ni++)
        acc[mi][ni] = __builtin_amdgcn_mfma_f32_16x16x32_bf16(
            af[mi], bfr[ni], acc[mi][ni], 0, 0, 0);

    __builtin_amdgcn_sched_barrier(0);
    __builtin_amdgcn_s_barrier();       // reads of cur done before re-stage
  }
#undef STAGE

  // ---- fused epilogue: + bias + PE, per-tensor transform, bf16 store ----
  // This wave's 64 output cols = exactly one head (d0 + wn*64 .. +63).
  float bias4[4];
#pragma unroll
  for (int ni=0;ni<4;ni++) bias4[ni] = bias[d0 + wn*64 + ni*16 + ln];

#pragma unroll
  for (int mi=0;mi<4;mi++){
#pragma unroll
    for (int r=0;r<4;r++){
      int m    = m0 + wm*64 + mi*16 + hi4*4 + r;
      int ntok = m & 1023;
      float vv[4];
#pragma unroll
      for (int ni=0;ni<4;ni++){
        int dd = d0 + wn*64 + ni*16 + ln;
        vv[ni] = acc[mi][ni][r] + bias4[ni] + pe[ntok*1024 + dd];
      }
      size_t base = (size_t)m*1024 + d0 + wn*64 + ln;
      if (z == 0){
        // softmax over the 64-dim head: 4 per-thread + 16-lane shfl group
        // (the 16-lane group = contiguous lanes sharing hi4 -> same row m)
        float ex0=__expf(vv[0]), ex1=__expf(vv[1]),
              ex2=__expf(vv[2]), ex3=__expf(vv[3]);
        float ps = ex0+ex1+ex2+ex3;
        ps += __shfl_xor(ps, 1); ps += __shfl_xor(ps, 2);
        ps += __shfl_xor(ps, 4); ps += __shfl_xor(ps, 8);
        float w = 1.0f / ps;
        tout[base +  0] = f2bf_bits(ex0*w);  tout[base + 16] = f2bf_bits(ex1*w);
        tout[base + 32] = f2bf_bits(ex2*w);  tout[base + 48] = f2bf_bits(ex3*w);
      } else if (z == 1){
        tout[base +  0] = f2bf_bits(__expf(vv[0]));
        tout[base + 16] = f2bf_bits(__expf(vv[1]));
        tout[base + 32] = f2bf_bits(__expf(vv[2]));
        tout[base + 48] = f2bf_bits(__expf(vv[3]));
      } else {
        tout[base +  0] = f2bf_bits(vv[0]); tout[base + 16] = f2bf_bits(vv[1]);
        tout[base + 32] = f2bf_bits(vv[2]); tout[base + 48] = f2bf_bits(vv[3]);
      }
    }
  }
}

// --------------------------- scores = ek^T v -------------------------------
// One block (512 threads = 16 waves) per (b,h).  ek,v read as bf16 (16 B
// per lane), converted to f32 in LDS.  Proven 2-phase dbuf skeleton over 16
// chunks of 64 tokens; npart in [0,8) splits tokens; two-step quadrant
// reduction; ksum folded; S stored normalized f32.   (proven r11-r15)

__global__ __launch_bounds__(512) void k_scores(
    const __bf16* __restrict__ t_bf, float* __restrict__ scoresOut)
{
  __shared__ __align__(16) float lds[4][4096];  // [0],[1]=ek dbuf; [2],[3]=v dbuf
  __shared__ float ksumLds[8][64];

  const int tid = threadIdx.x;                // 0..511
  const int bh  = blockIdx.x;
  const int b   = bh >> 4, h = bh & 15;
  const __bf16* kbase = t_bf + 16777216u + (size_t)b*1048576u + h*64;
  const __bf16* vbase = t_bf + 33554432u + (size_t)b*1048576u + h*64;

  const int dq = tid & 15, eg = (tid>>4) & 3, npart = tid >> 6;  // npart 0..7
  const int srow = tid >> 3;        // 0..63 (stage row; 8 threads/row)
  const int dcol = (tid & 7) * 8;   // bf16 elem col within the 64-dim slice

#define STAGE(BUF, CH) do{                                                \
    size_t g = (size_t)((CH)*64 + srow)*1024 + dcol;                      \
    bf16x8 k8 = *(const bf16x8*)(kbase + g);                              \
    bf16x8 v8 = *(const bf16x8*)(vbase + g);                              \
    f32x4 e0, e1, w0, w1;                                                 \
    e0[0]=(float)k8[0]; e0[1]=(float)k8[1]; e0[2]=(float)k8[2]; e0[3]=(float)k8[3]; \
    e1[0]=(float)k8[4]; e1[1]=(float)k8[5]; e1[2]=(float)k8[6]; e1[3]=(float)k8[7]; \
    w0[0]=(float)v8[0]; w0[1]=(float)v8[1]; w0[2]=(float)v8[2]; w0[3]=(float)v8[3]; \
    w1[0]=(float)v8[4]; w1[1]=(float)v8[5]; w1[2]=(float)v8[6]; w1[3]=(float)v8[7]; \
    *(f32x4*)(&lds[BUF][srow*64 + dcol])       = e0;                      \
    *(f32x4*)(&lds[BUF][srow*64 + dcol + 4])   = e1;                      \
    *(f32x4*)(&lds[2+(BUF)][srow*64 + dcol])     = w0;                    \
    *(f32x4*)(&lds[2+(BUF)][srow*64 + dcol + 4]) = w1;                    \
  }while(0)

  float acc[4][16] = {};
  float kp[4] = {0.f,0.f,0.f,0.f};

  STAGE(0, 0);
  __syncthreads();
  for (int ch=0; ch<16; ++ch){
    int cur = ch & 1;
    if (ch < 15) STAGE(cur^1, ch+1);   // writes OTHER buffer: safe vs compute
    for (int nn = npart; nn < 64; nn += 8){
      f32x4 ek4 = *(const f32x4*)(&lds[cur][nn*64 + dq*4]);
      f32x4 v0  = *(const f32x4*)(&lds[2+cur][nn*64 + eg*16 + 0]);
      f32x4 v1  = *(const f32x4*)(&lds[2+cur][nn*64 + eg*16 + 4]);
      f32x4 v2  = *(const f32x4*)(&lds[2+cur][nn*64 + eg*16 + 8]);
      f32x4 v3  = *(const f32x4*)(&lds[2+cur][nn*64 + eg*16 + 12]);
#pragma unroll
      for (int i2=0;i2<4;i2++){
        kp[i2] += ek4[i2];
#pragma unroll
        for (int j=0;j<4;j++){
          acc[i2][j+0]  += ek4[i2]*v0[j];
          acc[i2][j+4]  += ek4[i2]*v1[j];
          acc[i2][j+8]  += ek4[i2]*v2[j];
          acc[i2][j+12] += ek4[i2]*v3[j];
        }
      }
    }
    __syncthreads();
  }
#undef STAGE

  // kp identical across the 16 eg threads of a (dq,npart); eg==0 publishes.
  if (eg == 0){
#pragma unroll
    for (int i2=0;i2<4;i2++) ksumLds[npart][dq*4 + i2] = kp[i2];
  }

  // two-step quadrant reduction of the 8 token-part partial S tiles
  if (npart < 4){
    float* pb = &lds[npart][0];
#pragma unroll
    for (int i2=0;i2<4;i2++){
      int base = (dq*4 + i2)*64 + eg*16;
      f32x4 a0; a0[0]=acc[i2][0];  a0[1]=acc[i2][1];  a0[2]=acc[i2][2];  a0[3]=acc[i2][3];
      f32x4 a1; a1[0]=acc[i2][4];  a1[1]=acc[i2][5];  a1[2]=acc[i2][6];  a1[3]=acc[i2][7];
      f32x4 a2; a2[0]=acc[i2][8];  a2[1]=acc[i2][9];  a2[2]=acc[i2][10]; a2[3]=acc[i2][11];
      f32x4 a3; a3[0]=acc[i2][12]; a3[1]=acc[i2][13]; a3[2]=acc[i2][14]; a3[3]=acc[i2][15];
      *(f32x4*)(pb + base + 0)  = a0;
      *(f32x4*)(pb + base + 4)  = a1;
      *(f32x4*)(pb + base + 8)  = a2;
      *(f32x4*)(pb + base + 12) = a3;
    }
  }
  __syncthreads();
  if (npart >= 4){
    float* pb = &lds[npart-4][0];
#pragma unroll
    for (int i2=0;i2<4;i2++){
      int base = (dq*4 + i2)*64 + eg*16;
#pragma unroll
      for (int q=0;q<4;q++){
        f32x4 cu = *(const f32x4*)(pb + base + 4*q);
        cu[0]+=acc[i2][4*q+0]; cu[1]+=acc[i2][4*q+1];
        cu[2]+=acc[i2][4*q+2]; cu[3]+=acc[i2][4*q+3];
        *(f32x4*)(pb + base + 4*q) = cu;
      }
    }
  }
  __syncthreads();

  float* outp = scoresOut + (size_t)bh*4096;
#pragma unroll
  for (int i=0;i<2;i++){
    int idx = tid + 512*i;
    int q4  = idx*4;
    int d   = idx >> 4;
    float rk = 1.0f / (ksumLds[0][d]+ksumLds[1][d]+ksumLds[2][d]+ksumLds[3][d]
                      +ksumLds[4][d]+ksumLds[5][d]+ksumLds[6][d]+ksumLds[7][d]);
    f32x4 s = *(const f32x4*)(&lds[0][q4]) + *(const f32x4*)(&lds[1][q4])
            + *(const f32x4*)(&lds[2][q4]) + *(const f32x4*)(&lds[3][q4]);
    s[0]*=rk; s[1]*=rk; s[2]*=rk; s[3]*=rk;
    *(f32x4*)(outp + q4) = s;
  }
}

// --------------------------- ctx = qn @ S ----------------------------------
// Block = (b,h, 128-token chunk).  qn read as bf16x4 (8 B per lane),
// transpose-staged to f32 LDS; register-blocked matvec.   (proven r11-r15)

__global__ __launch_bounds__(256) void k_ctx(
    const __bf16* __restrict__ t_bf, const float* __restrict__ scoresIn,
    float* __restrict__ out)
{
  __shared__ __align__(16) float S[64*64];
  __shared__ __align__(16) float qnT[64*132];

  const int tid   = threadIdx.x;
  const int bh    = blockIdx.y;
  const int b     = bh >> 4, h = bh & 15;
  const int chunk = blockIdx.x;             // 0..7
  const __bf16* qbase = t_bf + (size_t)b*1048576u + h*64;

#pragma unroll
  for (int i=0;i<4;i++){
    int q4 = (tid + 256*i)*4;
    *(f32x4*)(S + q4) = *(const f32x4*)(scoresIn + (size_t)bh*4096 + q4);
  }

  const int lane = tid & 63, w = tid >> 6;
  const int pos = lane & 15, rq = lane >> 4;
#pragma unroll
  for (int p=0;p<8;p++){
    int nl = w*32 + p*4 + rq;
    int n  = chunk*128 + nl;
    bf16x4 qv = *(const bf16x4*)(qbase + (size_t)n*1024 + pos*4);
    qnT[(pos*4+0)*132 + nl] = (float)qv[0];
    qnT[(pos*4+1)*132 + nl] = (float)qv[1];
    qnT[(pos*4+2)*132 + nl] = (float)qv[2];
    qnT[(pos*4+3)*132 + nl] = (float)qv[3];
  }
  __syncthreads();

  const int eq = tid & 15, tg = tid >> 4;
  float acc[8][4] = {};
  for (int d=0; d<64; ++d){
    f32x4 s4 = *(const f32x4*)(S   + d*64  + eq*4);
    f32x4 q0 = *(const f32x4*)(qnT + d*132 + tg*8 + 0);
    f32x4 q1 = *(const f32x4*)(qnT + d*132 + tg*8 + 4);
#pragma unroll
    for (int j=0;j<4;j++){
      acc[0][j] += q0[0]*s4[j];
      acc[1][j] += q0[1]*s4[j];
      acc[2][j] += q0[2]*s4[j];
      acc[3][j] += q0[3]*s4[j];
      acc[4][j] += q1[0]*s4[j];
      acc[5][j] += q1[1]*s4[j];
      acc[6][j] += q1[2]*s4[j];
      acc[7][j] += q1[3]*s4[j];
    }
  }
#pragma unroll
  for (int i2=0;i2<8;i2++){
    int n = chunk*128 + tg*8 + i2;
    f32x4 o; o[0]=acc[i2][0]; o[1]=acc[i2][1]; o[2]=acc[i2][2]; o[3]=acc[i2][3];
    *(f32x4*)(out + (size_t)(b*1024 + n)*1024 + h*64 + eq*4) = o;
  }
}

// --------------------------- launcher --------------------------------------

extern "C" void kernel_launch(void* const* d_in, const int* in_sizes, int n_in,
                              void* d_out, int out_size, void* d_ws, size_t ws_size,
                              hipStream_t stream)
{
  const float* q_img = (const float*)d_in[0];
  const float* k_img = (const float*)d_in[1];
  const float* v_img = (const float*)d_in[2];
  const float* wq    = (const float*)d_in[3];
  const float* bq    = (const float*)d_in[4];
  const float* wk    = (const float*)d_in[5];
  const float* bk    = (const float*)d_in[6];
  const float* wv    = (const float*)d_in[7];
  const float* bv    = (const float*)d_in[8];
  float* out = (float*)d_out;
  char*  ws  = (char*)d_ws;

  unsigned short* t_bf   = (unsigned short*)ws;             // 96 MiB
  unsigned short* wbf    = (unsigned short*)(ws + 0x6000000);
  float*          pe     = (float*)(ws + 0x6480000);
  float*          scores = (float*)(ws + 0x6880000);
  unsigned short* x_bf   = (unsigned short*)(ws + 0x6C80000);  // 72 MiB

  k_prep_all<<<dim3(24832), dim3(256), 0, stream>>>(wq, wk, wv, wbf, pe,
                                                    q_img, k_img, v_img, x_bf);
  k_embed  <<<dim3(8,128,3), dim3(256), 0, stream>>>(x_bf, wbf,
                                                     bq,bk,bv, pe, t_bf);
  k_scores <<<dim3(256),  dim3(512), 0, stream>>>((const __bf16*)t_bf, scores);
  k_ctx    <<<dim3(8,256), dim3(256), 0, stream>>>((const __bf16*)t_bf, scores, out);
}